// Round 3
// baseline (2318.787 us; speedup 1.0000x reference)
//
#include <hip/hip_runtime.h>
#include <cstddef>

#define BB 8
#define NN 1024
#define KK 20
#define CCAT 169
#define NT 16  // n-tiles of 64 in final fused GEMM

// ---------------- neg dist, symmetric triangle tiles, norms fused in --------
// dist[b][n][m] = 2*sum_f x[f][n]*x[f][m] - ||x_n||^2 - ||x_m||^2  (symmetric)
__global__ __launch_bounds__(256) void dist_tile_kernel(
    const float* __restrict__ src, int bs, int F, float* __restrict__ dist) {
  __shared__ float As[8][128];
  __shared__ float Bs[8][128];
  int b = blockIdx.z;
  int rem = blockIdx.x, bi = 0;
  while (rem >= 8 - bi) { rem -= 8 - bi; ++bi; }
  int bj = bi + rem;
  int n0 = bi * 128;
  int m0 = bj * 128;
  int t = threadIdx.x;
  int tx = t & 15, ty = t >> 4;
  const float* p = src + (size_t)b * bs;

  float acc[8][8];
  float xn[8], xm[8];
#pragma unroll
  for (int i = 0; i < 8; ++i) {
    xn[i] = 0.f;
    xm[i] = 0.f;
#pragma unroll
    for (int j = 0; j < 8; ++j) acc[i][j] = 0.f;
  }

  int fr = t >> 5;
  int cc = (t & 31) << 2;
  for (int f0 = 0; f0 < F; f0 += 8) {
    int f = f0 + fr;
    float4 av = {0.f, 0.f, 0.f, 0.f}, bv = {0.f, 0.f, 0.f, 0.f};
    if (f < F) {
      av = *(const float4*)(p + (size_t)f * NN + n0 + cc);
      bv = *(const float4*)(p + (size_t)f * NN + m0 + cc);
    }
    __syncthreads();
    *(float4*)&As[fr][cc] = av;
    *(float4*)&Bs[fr][cc] = bv;
    __syncthreads();
#pragma unroll
    for (int f2 = 0; f2 < 8; ++f2) {
      float4 al = *(const float4*)&As[f2][ty << 2];
      float4 ah = *(const float4*)&As[f2][64 + (ty << 2)];
      float4 bl = *(const float4*)&Bs[f2][tx << 2];
      float4 bh = *(const float4*)&Bs[f2][64 + (tx << 2)];
      float a[8] = {al.x, al.y, al.z, al.w, ah.x, ah.y, ah.z, ah.w};
      float bb[8] = {bl.x, bl.y, bl.z, bl.w, bh.x, bh.y, bh.z, bh.w};
#pragma unroll
      for (int i = 0; i < 8; ++i) xn[i] += a[i] * a[i];
#pragma unroll
      for (int j = 0; j < 8; ++j) xm[j] += bb[j] * bb[j];
#pragma unroll
      for (int i = 0; i < 8; ++i)
#pragma unroll
        for (int j = 0; j < 8; ++j) acc[i][j] += a[i] * bb[j];
    }
  }

#pragma unroll
  for (int i = 0; i < 8; ++i)
#pragma unroll
    for (int j = 0; j < 8; ++j) acc[i][j] = 2.f * acc[i][j] - xn[i] - xm[j];

#pragma unroll
  for (int i = 0; i < 8; ++i) {
    int n = n0 + ((i < 4) ? ((ty << 2) + i) : (64 + (ty << 2) + i - 4));
    float* dr = dist + (((size_t)b * NN + n) << 10);
    *(float4*)(dr + m0 + (tx << 2)) =
        make_float4(acc[i][0], acc[i][1], acc[i][2], acc[i][3]);
    *(float4*)(dr + m0 + 64 + (tx << 2)) =
        make_float4(acc[i][4], acc[i][5], acc[i][6], acc[i][7]);
  }

  if (bi != bj) {
#pragma unroll
    for (int j = 0; j < 8; ++j) {
      int m = m0 + ((j < 4) ? ((tx << 2) + j) : (64 + (tx << 2) + j - 4));
      float* dr = dist + (((size_t)b * NN + m) << 10);
      *(float4*)(dr + n0 + (ty << 2)) =
          make_float4(acc[0][j], acc[1][j], acc[2][j], acc[3][j]);
      *(float4*)(dr + n0 + 64 + (ty << 2)) =
          make_float4(acc[4][j], acc[5][j], acc[6][j], acc[7][j]);
    }
  }
}

// ---------------- top-k (k=20) per row, one wave per row ----------------
__device__ __forceinline__ unsigned long long shfl_xor_u64(
    unsigned long long v, int off) {
  unsigned lo = (unsigned)v, hi = (unsigned)(v >> 32);
  lo = __shfl_xor(lo, off, 64);
  hi = __shfl_xor(hi, off, 64);
  return ((unsigned long long)hi << 32) | lo;
}

__global__ __launch_bounds__(256) void topk_kernel(
    const float* __restrict__ dist, int* __restrict__ idx_out) {
  int wave = threadIdx.x >> 6;
  int lane = threadIdx.x & 63;
  int row = blockIdx.x * 4 + wave;
  const float* d = dist + ((size_t)row << 10);

  unsigned long long key[16];
#pragma unroll
  for (int s = 0; s < 16; ++s) {
    int m = lane + (s << 6);
    unsigned u = __float_as_uint(d[m]);
    u = (u & 0x80000000u) ? ~u : (u | 0x80000000u);
    key[s] = ((unsigned long long)u << 32) | (unsigned)(NN - 1 - m);
  }

#pragma unroll
  for (int size = 2; size <= 16; size <<= 1) {
#pragma unroll
    for (int stride = size >> 1; stride > 0; stride >>= 1) {
#pragma unroll
      for (int i = 0; i < 16; ++i) {
        int j = i ^ stride;
        if (j > i) {
          unsigned long long a = key[i], c = key[j];
          bool desc = ((i & size) == 0);
          bool sw = desc ? (a < c) : (a > c);
          key[i] = sw ? c : a;
          key[j] = sw ? a : c;
        }
      }
    }
  }

  int* out = idx_out + row * KK;
  unsigned long long head = key[0];
  for (int r = 0; r < KK; ++r) {
    unsigned long long w = head;
#pragma unroll
    for (int off = 32; off > 0; off >>= 1) {
      unsigned long long o = shfl_xor_u64(w, off);
      if (o > w) w = o;
    }
    if (lane == 0) out[r] = (NN - 1) - (int)(w & 0xFFFFFFFFull);
    if (head == w) {
#pragma unroll
      for (int s = 0; s < 15; ++s) key[s] = key[s + 1];
      key[15] = 0ull;
      head = key[0];
    }
  }
}

// ---------------- fused transform + edge combine + mean over k --------------
// 512 threads / 8 waves per block: 2 waves/SIMD even at 1 block/CU, so the
// random-gather phase B gets latency overlap (was 1 wave/SIMD at 256 thr).
__global__ __launch_bounds__(512, 6) void edge_fused_kernel(
    const float* __restrict__ src, int bs, int D, int Co,
    const float* __restrict__ Wf, const float* __restrict__ Wd,
    const int* __restrict__ idx, int ooff, float* __restrict__ xcat) {
  __shared__ float2 Ulds[3 * NN];  // 24 KB {Uf,Ud}
  __shared__ float2 Vlds[3 * NN];  // 24 KB {Vf,Vd}
  __shared__ float4 Wlds[48];      // {wfa, wfb, wda, wdb} per i, D<=42
  int bo = blockIdx.x;
  int b = bo / Co, o = bo % Co;
  int t = threadIdx.x;

  if (t < D) {
    float wfa = Wf[o * 2 * D + t];
    float wfb = Wf[o * 2 * D + D + t] - wfa;
    float wda = Wd[o * 2 * D + t];
    float wdb = Wd[o * 2 * D + D + t] - wda;
    Wlds[t] = make_float4(wfa, wfb, wda, wdb);
  }
  __syncthreads();

  const float* sb = src + (size_t)b * bs;
  // phase A: 768 float4-groups over 3*NN positions, <=2 per thread
#pragma unroll
  for (int r = 0; r < 2; ++r) {
    int g = t + 512 * r;
    if (g < 3 * NN / 4) {
      float4 uf = {0.f, 0.f, 0.f, 0.f}, vf = {0.f, 0.f, 0.f, 0.f};
      float4 ud = {0.f, 0.f, 0.f, 0.f}, vd = {0.f, 0.f, 0.f, 0.f};
      for (int i = 0; i < D; ++i) {
        float4 s = *(const float4*)(sb + (size_t)i * 3 * NN + (g << 2));
        float4 w = Wlds[i];
        uf.x += w.x * s.x; uf.y += w.x * s.y; uf.z += w.x * s.z; uf.w += w.x * s.w;
        vf.x += w.y * s.x; vf.y += w.y * s.y; vf.z += w.y * s.z; vf.w += w.y * s.w;
        ud.x += w.z * s.x; ud.y += w.z * s.y; ud.z += w.z * s.z; ud.w += w.z * s.w;
        vd.x += w.w * s.x; vd.y += w.w * s.y; vd.z += w.w * s.z; vd.w += w.w * s.w;
      }
      *(float4*)&Ulds[(g << 2) + 0] = make_float4(uf.x, ud.x, uf.y, ud.y);
      *(float4*)&Ulds[(g << 2) + 2] = make_float4(uf.z, ud.z, uf.w, ud.w);
      *(float4*)&Vlds[(g << 2) + 0] = make_float4(vf.x, vd.x, vf.y, vd.y);
      *(float4*)&Vlds[(g << 2) + 2] = make_float4(vf.z, vd.z, vf.w, vd.w);
    }
  }
  __syncthreads();

  const float inv_k = 1.f / KK;
  // phase B: all 1024 n, 2 per thread
#pragma unroll
  for (int rep = 0; rep < 2; ++rep) {
    int n = rep * 512 + t;
    float2 v0 = Vlds[n];
    float2 v1 = Vlds[NN + n];
    float2 v2 = Vlds[2 * NN + n];
    const int4* ip = (const int4*)(idx + (b * NN + n) * KK);
    float a0 = 0.f, a1 = 0.f, a2 = 0.f;
#pragma unroll
    for (int q = 0; q < 5; ++q) {
      int4 iv = ip[q];
      int nbs[4] = {iv.x, iv.y, iv.z, iv.w};
#pragma unroll
      for (int jj = 0; jj < 4; ++jj) {
        int nb = nbs[jj];
        float2 u0 = Ulds[nb];
        float2 u1 = Ulds[NN + nb];
        float2 u2 = Ulds[2 * NN + nb];
        float pf0 = u0.x + v0.x, pd0 = u0.y + v0.y;
        float pf1 = u1.x + v1.x, pd1 = u1.y + v1.y;
        float pf2 = u2.x + v2.x, pd2 = u2.y + v2.y;
        float dot = pf0 * pd0 + pf1 * pd1 + pf2 * pd2;
        float dsq = pd0 * pd0 + pd1 * pd1 + pd2 * pd2;
        float g = (dot >= 0.f) ? 0.f : 0.8f * dot / (dsq + 1e-6f);
        a0 += pf0 - g * pd0;
        a1 += pf1 - g * pd1;
        a2 += pf2 - g * pd2;
      }
    }
    size_t ob = (size_t)b * CCAT * 3 * NN + (size_t)(ooff + o) * 3 * NN + n;
    xcat[ob] = a0 * inv_k;
    xcat[ob + NN] = a1 * inv_k;
    xcat[ob + 2 * NN] = a2 * inv_k;
  }
}

// ---------------- fused final GEMM + dvec + VN-leakyrelu + partial n-sum ----
// 512 threads / 8 waves: grid 768 = 3 blocks/CU -> 24 waves/CU (6/SIMD).
// Thread tile 2o x 4n x 3c (24 FMA per f2). dv[c][n] computed once per block
// by threads t<192 (register accumulator across tiles, not 32x redundant).
__global__ __launch_bounds__(512, 6) void final_fused_kernel(
    const float* __restrict__ xcat, const float* __restrict__ Wf4,
    const float* __restrict__ Wd4, float* __restrict__ part) {
  __shared__ float Ws[32][64];     // [f][o_col]
  __shared__ float Xs[3][32][64];  // [c][f][n_col]
  __shared__ float Wda[192];       // Wd4 padded to 6*32
  __shared__ float dvlds[192];     // dv[c][n] for the 64 n-cols
  int b = blockIdx.z;
  int o0 = blockIdx.y * 64;
  int n0 = blockIdx.x * 64;
  int t = threadIdx.x;
  int tx = t & 15, ty = t >> 4;  // compute: n = n0+tx*4+j, o = o0+ty*2+i
  int fr = t >> 4, fc = t & 15;  // staging: f-row, col-group

  if (t < 192) Wda[t] = (t < CCAT) ? Wd4[t] : 0.f;

  float acc[3][2][4];  // [c][o_i][n_j]
#pragma unroll
  for (int c = 0; c < 3; ++c)
#pragma unroll
    for (int i = 0; i < 2; ++i)
#pragma unroll
      for (int j = 0; j < 4; ++j) acc[c][i][j] = 0.f;
  float dvacc = 0.f;  // for t<192: owns (c=t>>6, n=t&63)
  int dc = t >> 6, dn = t & 63;

  const float* xb = xcat + (size_t)b * CCAT * 3 * NN;
  const int NTILE = (CCAT + 31) / 32;  // 6

  for (int tt = 0; tt < NTILE; ++tt) {
    int f = tt * 32 + fr;
    float4 xv[3];
    float wv[4];
#pragma unroll
    for (int c = 0; c < 3; ++c) {
      xv[c] = make_float4(0.f, 0.f, 0.f, 0.f);
      if (f < CCAT)
        xv[c] = *(const float4*)(xb + ((size_t)f * 3 + c) * NN + n0 + (fc << 2));
    }
#pragma unroll
    for (int q = 0; q < 4; ++q) {
      int o = o0 + (fc << 2) + q;
      wv[q] = (o < 341 && f < CCAT) ? Wf4[(size_t)o * CCAT + f] : 0.f;
    }
    __syncthreads();  // previous tile's compute + dv-pass done
#pragma unroll
    for (int c = 0; c < 3; ++c) *(float4*)&Xs[c][fr][fc << 2] = xv[c];
    *(float4*)&Ws[fr][fc << 2] = make_float4(wv[0], wv[1], wv[2], wv[3]);
    __syncthreads();
#pragma unroll
    for (int f2 = 0; f2 < 32; ++f2) {
      float2 w = *(const float2*)&Ws[f2][ty << 1];
#pragma unroll
      for (int c = 0; c < 3; ++c) {
        float4 x = *(const float4*)&Xs[c][f2][tx << 2];
        float xa[4] = {x.x, x.y, x.z, x.w};
#pragma unroll
        for (int j = 0; j < 4; ++j) {
          acc[c][0][j] += w.x * xa[j];
          acc[c][1][j] += w.y * xa[j];
        }
      }
    }
    if (t < 192) {
#pragma unroll
      for (int f2 = 0; f2 < 32; ++f2)
        dvacc += Wda[tt * 32 + f2] * Xs[dc][f2][dn];
    }
  }

  if (t < 192) dvlds[t] = dvacc;
  __syncthreads();
  float dvv[3][4];
#pragma unroll
  for (int c = 0; c < 3; ++c)
#pragma unroll
    for (int j = 0; j < 4; ++j) dvv[c][j] = dvlds[c * 64 + (tx << 2) + j];

  float s[3][2];
#pragma unroll
  for (int c = 0; c < 3; ++c)
#pragma unroll
    for (int i = 0; i < 2; ++i) s[c][i] = 0.f;
#pragma unroll
  for (int i = 0; i < 2; ++i) {
#pragma unroll
    for (int j = 0; j < 4; ++j) {
      float d0 = dvv[0][j], d1 = dvv[1][j], d2 = dvv[2][j];
      float p0 = acc[0][i][j], p1 = acc[1][i][j], p2 = acc[2][i][j];
      float dot = p0 * d0 + p1 * d1 + p2 * d2;
      float dsq = d0 * d0 + d1 * d1 + d2 * d2;
      float g = (dot >= 0.f) ? 0.f : 0.8f * dot / (dsq + 1e-6f);
      s[0][i] += p0 - g * d0;
      s[1][i] += p1 - g * d1;
      s[2][i] += p2 - g * d2;
    }
  }

#pragma unroll
  for (int off = 1; off < 16; off <<= 1) {
#pragma unroll
    for (int c = 0; c < 3; ++c)
#pragma unroll
      for (int i = 0; i < 2; ++i) s[c][i] += __shfl_xor(s[c][i], off, 64);
  }
  if (tx == 0) {
#pragma unroll
    for (int i = 0; i < 2; ++i) {
      int o = o0 + (ty << 1) + i;
      if (o < 341) {
#pragma unroll
        for (int c = 0; c < 3; ++c)
          part[(((size_t)b * 341 + o) * 3 + c) * NT + blockIdx.x] = s[c][i];
      }
    }
  }
}

__global__ void final_reduce_kernel(const float* __restrict__ part,
                                    float* __restrict__ out) {
  int t = blockIdx.x * 256 + threadIdx.x;
  if (t >= BB * 341 * 3) return;
  const float* p = part + (size_t)t * NT;
  float s = 0.f;
#pragma unroll
  for (int nt = 0; nt < NT; ++nt) s += p[nt];
  out[t] = s * (1.f / 1024.f);
}

extern "C" void kernel_launch(void* const* d_in, const int* in_sizes, int n_in,
                              void* d_out, int out_size, void* d_ws,
                              size_t ws_size, hipStream_t stream) {
  (void)in_sizes; (void)n_in; (void)out_size; (void)ws_size;
  const float* x = (const float*)d_in[0];
  const float* Wf[5] = {(const float*)d_in[1], (const float*)d_in[3],
                        (const float*)d_in[5], (const float*)d_in[7],
                        (const float*)d_in[9]};
  const float* Wd[5] = {(const float*)d_in[2], (const float*)d_in[4],
                        (const float*)d_in[6], (const float*)d_in[8],
                        (const float*)d_in[10]};

  float* ws = (float*)d_ws;
  float* dist = ws;
  float* part = ws;  // dist region dead once final_fused runs
  size_t off = (size_t)BB * NN * NN;
  int* idx = (int*)(ws + off);
  off += (size_t)BB * NN * KK;
  float* xcat = ws + off;

  struct LayerCfg { int D, Co, inoff, ooff; };
  const LayerCfg L[4] = {
      {1, 21, 0, 0},
      {21, 21, 0, 21},
      {21, 42, 21, 42},
      {42, 85, 42, 84},
  };

  for (int l = 0; l < 4; ++l) {
    const float* src = (l == 0) ? x : (xcat + (size_t)L[l].inoff * 3 * NN);
    int bs = (l == 0) ? 3 * NN : CCAT * 3 * NN;
    int D = L[l].D, Co = L[l].Co;

    dist_tile_kernel<<<dim3(36, 1, BB), 256, 0, stream>>>(src, bs, 3 * D, dist);
    topk_kernel<<<(BB * NN) / 4, 256, 0, stream>>>(dist, idx);
    edge_fused_kernel<<<BB * Co, 512, 0, stream>>>(src, bs, D, Co, Wf[l],
                                                   Wd[l], idx, L[l].ooff,
                                                   xcat);
  }

  final_fused_kernel<<<dim3(NT, 6, BB), 512, 0, stream>>>(xcat, Wf[4], Wd[4],
                                                          part);
  final_reduce_kernel<<<(BB * 341 * 3 + 255) / 256, 256, 0, stream>>>(
      part, (float*)d_out);
}

// Round 4
// 1982.639 us; speedup vs baseline: 1.1695x; 1.1695x over previous
//
#include <hip/hip_runtime.h>
#include <cstddef>

#define BB 8
#define NN 1024
#define KK 20
#define CCAT 169
#define NT 16  // n-tiles of 64 in final fused GEMM

// ---------------- neg dist, symmetric triangle tiles, norms fused in --------
// dist[b][n][m] = 2*sum_f x[f][n]*x[f][m] - ||x_n||^2 - ||x_m||^2  (symmetric)
__global__ __launch_bounds__(256) void dist_tile_kernel(
    const float* __restrict__ src, int bs, int F, float* __restrict__ dist) {
  __shared__ float As[8][128];
  __shared__ float Bs[8][128];
  int b = blockIdx.z;
  int rem = blockIdx.x, bi = 0;
  while (rem >= 8 - bi) { rem -= 8 - bi; ++bi; }
  int bj = bi + rem;
  int n0 = bi * 128;
  int m0 = bj * 128;
  int t = threadIdx.x;
  int tx = t & 15, ty = t >> 4;
  const float* p = src + (size_t)b * bs;

  float acc[8][8];
  float xn[8], xm[8];
#pragma unroll
  for (int i = 0; i < 8; ++i) {
    xn[i] = 0.f;
    xm[i] = 0.f;
#pragma unroll
    for (int j = 0; j < 8; ++j) acc[i][j] = 0.f;
  }

  int fr = t >> 5;
  int cc = (t & 31) << 2;
  for (int f0 = 0; f0 < F; f0 += 8) {
    int f = f0 + fr;
    float4 av = {0.f, 0.f, 0.f, 0.f}, bv = {0.f, 0.f, 0.f, 0.f};
    if (f < F) {
      av = *(const float4*)(p + (size_t)f * NN + n0 + cc);
      bv = *(const float4*)(p + (size_t)f * NN + m0 + cc);
    }
    __syncthreads();
    *(float4*)&As[fr][cc] = av;
    *(float4*)&Bs[fr][cc] = bv;
    __syncthreads();
#pragma unroll
    for (int f2 = 0; f2 < 8; ++f2) {
      float4 al = *(const float4*)&As[f2][ty << 2];
      float4 ah = *(const float4*)&As[f2][64 + (ty << 2)];
      float4 bl = *(const float4*)&Bs[f2][tx << 2];
      float4 bh = *(const float4*)&Bs[f2][64 + (tx << 2)];
      float a[8] = {al.x, al.y, al.z, al.w, ah.x, ah.y, ah.z, ah.w};
      float bb[8] = {bl.x, bl.y, bl.z, bl.w, bh.x, bh.y, bh.z, bh.w};
#pragma unroll
      for (int i = 0; i < 8; ++i) xn[i] += a[i] * a[i];
#pragma unroll
      for (int j = 0; j < 8; ++j) xm[j] += bb[j] * bb[j];
#pragma unroll
      for (int i = 0; i < 8; ++i)
#pragma unroll
        for (int j = 0; j < 8; ++j) acc[i][j] += a[i] * bb[j];
    }
  }

#pragma unroll
  for (int i = 0; i < 8; ++i)
#pragma unroll
    for (int j = 0; j < 8; ++j) acc[i][j] = 2.f * acc[i][j] - xn[i] - xm[j];

#pragma unroll
  for (int i = 0; i < 8; ++i) {
    int n = n0 + ((i < 4) ? ((ty << 2) + i) : (64 + (ty << 2) + i - 4));
    float* dr = dist + (((size_t)b * NN + n) << 10);
    *(float4*)(dr + m0 + (tx << 2)) =
        make_float4(acc[i][0], acc[i][1], acc[i][2], acc[i][3]);
    *(float4*)(dr + m0 + 64 + (tx << 2)) =
        make_float4(acc[i][4], acc[i][5], acc[i][6], acc[i][7]);
  }

  if (bi != bj) {
#pragma unroll
    for (int j = 0; j < 8; ++j) {
      int m = m0 + ((j < 4) ? ((tx << 2) + j) : (64 + (tx << 2) + j - 4));
      float* dr = dist + (((size_t)b * NN + m) << 10);
      *(float4*)(dr + n0 + (ty << 2)) =
          make_float4(acc[0][j], acc[1][j], acc[2][j], acc[3][j]);
      *(float4*)(dr + n0 + 64 + (ty << 2)) =
          make_float4(acc[4][j], acc[5][j], acc[6][j], acc[7][j]);
    }
  }
}

// ---------------- top-k (k=20) per row, one wave per row ----------------
__device__ __forceinline__ unsigned long long shfl_xor_u64(
    unsigned long long v, int off) {
  unsigned lo = (unsigned)v, hi = (unsigned)(v >> 32);
  lo = __shfl_xor(lo, off, 64);
  hi = __shfl_xor(hi, off, 64);
  return ((unsigned long long)hi << 32) | lo;
}

__global__ __launch_bounds__(256) void topk_kernel(
    const float* __restrict__ dist, int* __restrict__ idx_out) {
  int wave = threadIdx.x >> 6;
  int lane = threadIdx.x & 63;
  int row = blockIdx.x * 4 + wave;
  const float* d = dist + ((size_t)row << 10);

  unsigned long long key[16];
#pragma unroll
  for (int s = 0; s < 16; ++s) {
    int m = lane + (s << 6);
    unsigned u = __float_as_uint(d[m]);
    u = (u & 0x80000000u) ? ~u : (u | 0x80000000u);
    key[s] = ((unsigned long long)u << 32) | (unsigned)(NN - 1 - m);
  }

#pragma unroll
  for (int size = 2; size <= 16; size <<= 1) {
#pragma unroll
    for (int stride = size >> 1; stride > 0; stride >>= 1) {
#pragma unroll
      for (int i = 0; i < 16; ++i) {
        int j = i ^ stride;
        if (j > i) {
          unsigned long long a = key[i], c = key[j];
          bool desc = ((i & size) == 0);
          bool sw = desc ? (a < c) : (a > c);
          key[i] = sw ? c : a;
          key[j] = sw ? a : c;
        }
      }
    }
  }

  int* out = idx_out + row * KK;
  unsigned long long head = key[0];
  for (int r = 0; r < KK; ++r) {
    unsigned long long w = head;
#pragma unroll
    for (int off = 32; off > 0; off >>= 1) {
      unsigned long long o = shfl_xor_u64(w, off);
      if (o > w) w = o;
    }
    if (lane == 0) out[r] = (NN - 1) - (int)(w & 0xFFFFFFFFull);
    if (head == w) {
#pragma unroll
      for (int s = 0; s < 15; ++s) key[s] = key[s + 1];
      key[15] = 0ull;
      head = key[0];
    }
  }
}

// ---------------- fused transform + edge combine + mean over k --------------
// 512 threads / 8 waves per block. NOTE (R3 lesson): min-waves hint must stay
// low — (512,6) capped VGPR at ~85 and the allocator spilled everything to
// scratch (4 GB of HBM writes, 22x slowdown). (512,4) caps at 128: safe.
__global__ __launch_bounds__(512, 4) void edge_fused_kernel(
    const float* __restrict__ src, int bs, int D, int Co,
    const float* __restrict__ Wf, const float* __restrict__ Wd,
    const int* __restrict__ idx, int ooff, float* __restrict__ xcat) {
  __shared__ float2 Ulds[3 * NN];  // 24 KB {Uf,Ud}
  __shared__ float2 Vlds[3 * NN];  // 24 KB {Vf,Vd}
  __shared__ float4 Wlds[48];      // {wfa, wfb, wda, wdb} per i, D<=42
  int bo = blockIdx.x;
  int b = bo / Co, o = bo % Co;
  int t = threadIdx.x;

  if (t < D) {
    float wfa = Wf[o * 2 * D + t];
    float wfb = Wf[o * 2 * D + D + t] - wfa;
    float wda = Wd[o * 2 * D + t];
    float wdb = Wd[o * 2 * D + D + t] - wda;
    Wlds[t] = make_float4(wfa, wfb, wda, wdb);
  }
  __syncthreads();

  const float* sb = src + (size_t)b * bs;
  // phase A: 768 float4-groups over 3*NN positions, <=2 per thread
#pragma unroll
  for (int r = 0; r < 2; ++r) {
    int g = t + 512 * r;
    if (g < 3 * NN / 4) {
      float4 uf = {0.f, 0.f, 0.f, 0.f}, vf = {0.f, 0.f, 0.f, 0.f};
      float4 ud = {0.f, 0.f, 0.f, 0.f}, vd = {0.f, 0.f, 0.f, 0.f};
      for (int i = 0; i < D; ++i) {
        float4 s = *(const float4*)(sb + (size_t)i * 3 * NN + (g << 2));
        float4 w = Wlds[i];
        uf.x += w.x * s.x; uf.y += w.x * s.y; uf.z += w.x * s.z; uf.w += w.x * s.w;
        vf.x += w.y * s.x; vf.y += w.y * s.y; vf.z += w.y * s.z; vf.w += w.y * s.w;
        ud.x += w.z * s.x; ud.y += w.z * s.y; ud.z += w.z * s.z; ud.w += w.z * s.w;
        vd.x += w.w * s.x; vd.y += w.w * s.y; vd.z += w.w * s.z; vd.w += w.w * s.w;
      }
      *(float4*)&Ulds[(g << 2) + 0] = make_float4(uf.x, ud.x, uf.y, ud.y);
      *(float4*)&Ulds[(g << 2) + 2] = make_float4(uf.z, ud.z, uf.w, ud.w);
      *(float4*)&Vlds[(g << 2) + 0] = make_float4(vf.x, vd.x, vf.y, vd.y);
      *(float4*)&Vlds[(g << 2) + 2] = make_float4(vf.z, vd.z, vf.w, vd.w);
    }
  }
  __syncthreads();

  const float inv_k = 1.f / KK;
  // phase B: all 1024 n, 2 per thread
#pragma unroll
  for (int rep = 0; rep < 2; ++rep) {
    int n = rep * 512 + t;
    float2 v0 = Vlds[n];
    float2 v1 = Vlds[NN + n];
    float2 v2 = Vlds[2 * NN + n];
    const int4* ip = (const int4*)(idx + (b * NN + n) * KK);
    float a0 = 0.f, a1 = 0.f, a2 = 0.f;
#pragma unroll
    for (int q = 0; q < 5; ++q) {
      int4 iv = ip[q];
      int nbs[4] = {iv.x, iv.y, iv.z, iv.w};
#pragma unroll
      for (int jj = 0; jj < 4; ++jj) {
        int nb = nbs[jj];
        float2 u0 = Ulds[nb];
        float2 u1 = Ulds[NN + nb];
        float2 u2 = Ulds[2 * NN + nb];
        float pf0 = u0.x + v0.x, pd0 = u0.y + v0.y;
        float pf1 = u1.x + v1.x, pd1 = u1.y + v1.y;
        float pf2 = u2.x + v2.x, pd2 = u2.y + v2.y;
        float dot = pf0 * pd0 + pf1 * pd1 + pf2 * pd2;
        float dsq = pd0 * pd0 + pd1 * pd1 + pd2 * pd2;
        float g = (dot >= 0.f) ? 0.f : 0.8f * dot / (dsq + 1e-6f);
        a0 += pf0 - g * pd0;
        a1 += pf1 - g * pd1;
        a2 += pf2 - g * pd2;
      }
    }
    size_t ob = (size_t)b * CCAT * 3 * NN + (size_t)(ooff + o) * 3 * NN + n;
    xcat[ob] = a0 * inv_k;
    xcat[ob + NN] = a1 * inv_k;
    xcat[ob + 2 * NN] = a2 * inv_k;
  }
}

// ---------------- fused final GEMM + dvec + VN-leakyrelu + partial n-sum ----
// 512 threads / 8 waves. Thread tile 2o x 4n x 3c (24 FMA per f2). dv[c][n]
// computed once per block by threads t<192. (512,4) not (512,6) — R3 lesson.
__global__ __launch_bounds__(512, 4) void final_fused_kernel(
    const float* __restrict__ xcat, const float* __restrict__ Wf4,
    const float* __restrict__ Wd4, float* __restrict__ part) {
  __shared__ float Ws[32][64];     // [f][o_col]
  __shared__ float Xs[3][32][64];  // [c][f][n_col]
  __shared__ float Wda[192];       // Wd4 padded to 6*32
  __shared__ float dvlds[192];     // dv[c][n] for the 64 n-cols
  int b = blockIdx.z;
  int o0 = blockIdx.y * 64;
  int n0 = blockIdx.x * 64;
  int t = threadIdx.x;
  int tx = t & 15, ty = t >> 4;  // compute: n = n0+tx*4+j, o = o0+ty*2+i
  int fr = t >> 4, fc = t & 15;  // staging: f-row, col-group

  if (t < 192) Wda[t] = (t < CCAT) ? Wd4[t] : 0.f;

  float acc[3][2][4];  // [c][o_i][n_j]
#pragma unroll
  for (int c = 0; c < 3; ++c)
#pragma unroll
    for (int i = 0; i < 2; ++i)
#pragma unroll
      for (int j = 0; j < 4; ++j) acc[c][i][j] = 0.f;
  float dvacc = 0.f;  // for t<192: owns (c=t>>6, n=t&63)
  int dc = t >> 6, dn = t & 63;

  const float* xb = xcat + (size_t)b * CCAT * 3 * NN;
  const int NTILE = (CCAT + 31) / 32;  // 6

  for (int tt = 0; tt < NTILE; ++tt) {
    int f = tt * 32 + fr;
    float4 xv[3];
    float wv[4];
#pragma unroll
    for (int c = 0; c < 3; ++c) {
      xv[c] = make_float4(0.f, 0.f, 0.f, 0.f);
      if (f < CCAT)
        xv[c] = *(const float4*)(xb + ((size_t)f * 3 + c) * NN + n0 + (fc << 2));
    }
#pragma unroll
    for (int q = 0; q < 4; ++q) {
      int o = o0 + (fc << 2) + q;
      wv[q] = (o < 341 && f < CCAT) ? Wf4[(size_t)o * CCAT + f] : 0.f;
    }
    __syncthreads();  // previous tile's compute + dv-pass done
#pragma unroll
    for (int c = 0; c < 3; ++c) *(float4*)&Xs[c][fr][fc << 2] = xv[c];
    *(float4*)&Ws[fr][fc << 2] = make_float4(wv[0], wv[1], wv[2], wv[3]);
    __syncthreads();
#pragma unroll
    for (int f2 = 0; f2 < 32; ++f2) {
      float2 w = *(const float2*)&Ws[f2][ty << 1];
#pragma unroll
      for (int c = 0; c < 3; ++c) {
        float4 x = *(const float4*)&Xs[c][f2][tx << 2];
        float xa[4] = {x.x, x.y, x.z, x.w};
#pragma unroll
        for (int j = 0; j < 4; ++j) {
          acc[c][0][j] += w.x * xa[j];
          acc[c][1][j] += w.y * xa[j];
        }
      }
    }
    if (t < 192) {
#pragma unroll
      for (int f2 = 0; f2 < 32; ++f2)
        dvacc += Wda[tt * 32 + f2] * Xs[dc][f2][dn];
    }
  }

  if (t < 192) dvlds[t] = dvacc;
  __syncthreads();
  float dvv[3][4];
#pragma unroll
  for (int c = 0; c < 3; ++c)
#pragma unroll
    for (int j = 0; j < 4; ++j) dvv[c][j] = dvlds[c * 64 + (tx << 2) + j];

  float s[3][2];
#pragma unroll
  for (int c = 0; c < 3; ++c)
#pragma unroll
    for (int i = 0; i < 2; ++i) s[c][i] = 0.f;
#pragma unroll
  for (int i = 0; i < 2; ++i) {
#pragma unroll
    for (int j = 0; j < 4; ++j) {
      float d0 = dvv[0][j], d1 = dvv[1][j], d2 = dvv[2][j];
      float p0 = acc[0][i][j], p1 = acc[1][i][j], p2 = acc[2][i][j];
      float dot = p0 * d0 + p1 * d1 + p2 * d2;
      float dsq = d0 * d0 + d1 * d1 + d2 * d2;
      float g = (dot >= 0.f) ? 0.f : 0.8f * dot / (dsq + 1e-6f);
      s[0][i] += p0 - g * d0;
      s[1][i] += p1 - g * d1;
      s[2][i] += p2 - g * d2;
    }
  }

#pragma unroll
  for (int off = 1; off < 16; off <<= 1) {
#pragma unroll
    for (int c = 0; c < 3; ++c)
#pragma unroll
      for (int i = 0; i < 2; ++i) s[c][i] += __shfl_xor(s[c][i], off, 64);
  }
  if (tx == 0) {
#pragma unroll
    for (int i = 0; i < 2; ++i) {
      int o = o0 + (ty << 1) + i;
      if (o < 341) {
#pragma unroll
        for (int c = 0; c < 3; ++c)
          part[(((size_t)b * 341 + o) * 3 + c) * NT + blockIdx.x] = s[c][i];
      }
    }
  }
}

__global__ void final_reduce_kernel(const float* __restrict__ part,
                                    float* __restrict__ out) {
  int t = blockIdx.x * 256 + threadIdx.x;
  if (t >= BB * 341 * 3) return;
  const float* p = part + (size_t)t * NT;
  float s = 0.f;
#pragma unroll
  for (int nt = 0; nt < NT; ++nt) s += p[nt];
  out[t] = s * (1.f / 1024.f);
}

extern "C" void kernel_launch(void* const* d_in, const int* in_sizes, int n_in,
                              void* d_out, int out_size, void* d_ws,
                              size_t ws_size, hipStream_t stream) {
  (void)in_sizes; (void)n_in; (void)out_size; (void)ws_size;
  const float* x = (const float*)d_in[0];
  const float* Wf[5] = {(const float*)d_in[1], (const float*)d_in[3],
                        (const float*)d_in[5], (const float*)d_in[7],
                        (const float*)d_in[9]};
  const float* Wd[5] = {(const float*)d_in[2], (const float*)d_in[4],
                        (const float*)d_in[6], (const float*)d_in[8],
                        (const float*)d_in[10]};

  float* ws = (float*)d_ws;
  float* dist = ws;
  float* part = ws;  // dist region dead once final_fused runs
  size_t off = (size_t)BB * NN * NN;
  int* idx = (int*)(ws + off);
  off += (size_t)BB * NN * KK;
  float* xcat = ws + off;

  struct LayerCfg { int D, Co, inoff, ooff; };
  const LayerCfg L[4] = {
      {1, 21, 0, 0},
      {21, 21, 0, 21},
      {21, 42, 21, 42},
      {42, 85, 42, 84},
  };

  for (int l = 0; l < 4; ++l) {
    const float* src = (l == 0) ? x : (xcat + (size_t)L[l].inoff * 3 * NN);
    int bs = (l == 0) ? 3 * NN : CCAT * 3 * NN;
    int D = L[l].D, Co = L[l].Co;

    dist_tile_kernel<<<dim3(36, 1, BB), 256, 0, stream>>>(src, bs, 3 * D, dist);
    topk_kernel<<<(BB * NN) / 4, 256, 0, stream>>>(dist, idx);
    edge_fused_kernel<<<BB * Co, 512, 0, stream>>>(src, bs, D, Co, Wf[l],
                                                   Wd[l], idx, L[l].ooff,
                                                   xcat);
  }

  final_fused_kernel<<<dim3(NT, 6, BB), 512, 0, stream>>>(xcat, Wf[4], Wd[4],
                                                          part);
  final_reduce_kernel<<<(BB * 341 * 3 + 255) / 256, 256, 0, stream>>>(
      part, (float*)d_out);
}

// Round 5
// 1103.694 us; speedup vs baseline: 2.1009x; 1.7964x over previous
//
#include <hip/hip_runtime.h>
#include <cstddef>

#define BB 8
#define NN 1024
#define KK 20
#define CCAT 169
#define NT 16  // n-tiles of 64 in final fused GEMM

// ---------------- neg dist, symmetric triangle tiles, norms fused in --------
// dist[b][n][m] = 2*sum_f x[f][n]*x[f][m] - ||x_n||^2 - ||x_m||^2  (symmetric)
__global__ __launch_bounds__(256) void dist_tile_kernel(
    const float* __restrict__ src, int bs, int F, float* __restrict__ dist) {
  __shared__ float As[8][128];
  __shared__ float Bs[8][128];
  int b = blockIdx.z;
  int rem = blockIdx.x, bi = 0;
  while (rem >= 8 - bi) { rem -= 8 - bi; ++bi; }
  int bj = bi + rem;
  int n0 = bi * 128;
  int m0 = bj * 128;
  int t = threadIdx.x;
  int tx = t & 15, ty = t >> 4;
  const float* p = src + (size_t)b * bs;

  float acc[8][8];
  float xn[8], xm[8];
#pragma unroll
  for (int i = 0; i < 8; ++i) {
    xn[i] = 0.f;
    xm[i] = 0.f;
#pragma unroll
    for (int j = 0; j < 8; ++j) acc[i][j] = 0.f;
  }

  int fr = t >> 5;
  int cc = (t & 31) << 2;
  for (int f0 = 0; f0 < F; f0 += 8) {
    int f = f0 + fr;
    float4 av = {0.f, 0.f, 0.f, 0.f}, bv = {0.f, 0.f, 0.f, 0.f};
    if (f < F) {
      av = *(const float4*)(p + (size_t)f * NN + n0 + cc);
      bv = *(const float4*)(p + (size_t)f * NN + m0 + cc);
    }
    __syncthreads();
    *(float4*)&As[fr][cc] = av;
    *(float4*)&Bs[fr][cc] = bv;
    __syncthreads();
#pragma unroll
    for (int f2 = 0; f2 < 8; ++f2) {
      float4 al = *(const float4*)&As[f2][ty << 2];
      float4 ah = *(const float4*)&As[f2][64 + (ty << 2)];
      float4 bl = *(const float4*)&Bs[f2][tx << 2];
      float4 bh = *(const float4*)&Bs[f2][64 + (tx << 2)];
      float a[8] = {al.x, al.y, al.z, al.w, ah.x, ah.y, ah.z, ah.w};
      float bb[8] = {bl.x, bl.y, bl.z, bl.w, bh.x, bh.y, bh.z, bh.w};
#pragma unroll
      for (int i = 0; i < 8; ++i) xn[i] += a[i] * a[i];
#pragma unroll
      for (int j = 0; j < 8; ++j) xm[j] += bb[j] * bb[j];
#pragma unroll
      for (int i = 0; i < 8; ++i)
#pragma unroll
        for (int j = 0; j < 8; ++j) acc[i][j] += a[i] * bb[j];
    }
  }

#pragma unroll
  for (int i = 0; i < 8; ++i)
#pragma unroll
    for (int j = 0; j < 8; ++j) acc[i][j] = 2.f * acc[i][j] - xn[i] - xm[j];

#pragma unroll
  for (int i = 0; i < 8; ++i) {
    int n = n0 + ((i < 4) ? ((ty << 2) + i) : (64 + (ty << 2) + i - 4));
    float* dr = dist + (((size_t)b * NN + n) << 10);
    *(float4*)(dr + m0 + (tx << 2)) =
        make_float4(acc[i][0], acc[i][1], acc[i][2], acc[i][3]);
    *(float4*)(dr + m0 + 64 + (tx << 2)) =
        make_float4(acc[i][4], acc[i][5], acc[i][6], acc[i][7]);
  }

  if (bi != bj) {
#pragma unroll
    for (int j = 0; j < 8; ++j) {
      int m = m0 + ((j < 4) ? ((tx << 2) + j) : (64 + (tx << 2) + j - 4));
      float* dr = dist + (((size_t)b * NN + m) << 10);
      *(float4*)(dr + n0 + (ty << 2)) =
          make_float4(acc[0][j], acc[1][j], acc[2][j], acc[3][j]);
      *(float4*)(dr + n0 + 64 + (ty << 2)) =
          make_float4(acc[4][j], acc[5][j], acc[6][j], acc[7][j]);
    }
  }
}

// ---------------- top-k (k=20) per row, one wave per row ----------------
__device__ __forceinline__ unsigned long long shfl_xor_u64(
    unsigned long long v, int off) {
  unsigned lo = (unsigned)v, hi = (unsigned)(v >> 32);
  lo = __shfl_xor(lo, off, 64);
  hi = __shfl_xor(hi, off, 64);
  return ((unsigned long long)hi << 32) | lo;
}

__global__ __launch_bounds__(256) void topk_kernel(
    const float* __restrict__ dist, int* __restrict__ idx_out) {
  int wave = threadIdx.x >> 6;
  int lane = threadIdx.x & 63;
  int row = blockIdx.x * 4 + wave;
  const float* d = dist + ((size_t)row << 10);

  unsigned long long key[16];
#pragma unroll
  for (int s = 0; s < 16; ++s) {
    int m = lane + (s << 6);
    unsigned u = __float_as_uint(d[m]);
    u = (u & 0x80000000u) ? ~u : (u | 0x80000000u);
    key[s] = ((unsigned long long)u << 32) | (unsigned)(NN - 1 - m);
  }

#pragma unroll
  for (int size = 2; size <= 16; size <<= 1) {
#pragma unroll
    for (int stride = size >> 1; stride > 0; stride >>= 1) {
#pragma unroll
      for (int i = 0; i < 16; ++i) {
        int j = i ^ stride;
        if (j > i) {
          unsigned long long a = key[i], c = key[j];
          bool desc = ((i & size) == 0);
          bool sw = desc ? (a < c) : (a > c);
          key[i] = sw ? c : a;
          key[j] = sw ? a : c;
        }
      }
    }
  }

  int* out = idx_out + row * KK;
  unsigned long long head = key[0];
  for (int r = 0; r < KK; ++r) {
    unsigned long long w = head;
#pragma unroll
    for (int off = 32; off > 0; off >>= 1) {
      unsigned long long o = shfl_xor_u64(w, off);
      if (o > w) w = o;
    }
    if (lane == 0) out[r] = (NN - 1) - (int)(w & 0xFFFFFFFFull);
    if (head == w) {
#pragma unroll
      for (int s = 0; s < 15; ++s) key[s] = key[s + 1];
      key[15] = 0ull;
      head = key[0];
    }
  }
}

// ---------------- fused transform + edge combine + mean over k --------------
// 512 threads / 8 waves per block.
// R3/R4 LESSON: hipcc treats __launch_bounds__'s 2nd arg as min BLOCKS/CU
// (CUDA semantics): (512,4) forced 2048 thr/CU -> 64-VGPR cap -> full spill
// (3.5 GB scratch traffic). NO second arg: allocator uses natural VGPR count.
__global__ __launch_bounds__(512) void edge_fused_kernel(
    const float* __restrict__ src, int bs, int D, int Co,
    const float* __restrict__ Wf, const float* __restrict__ Wd,
    const int* __restrict__ idx, int ooff, float* __restrict__ xcat) {
  __shared__ float2 Ulds[3 * NN];  // 24 KB {Uf,Ud}
  __shared__ float2 Vlds[3 * NN];  // 24 KB {Vf,Vd}
  __shared__ float4 Wlds[48];      // {wfa, wfb, wda, wdb} per i, D<=42
  int bo = blockIdx.x;
  int b = bo / Co, o = bo % Co;
  int t = threadIdx.x;

  if (t < D) {
    float wfa = Wf[o * 2 * D + t];
    float wfb = Wf[o * 2 * D + D + t] - wfa;
    float wda = Wd[o * 2 * D + t];
    float wdb = Wd[o * 2 * D + D + t] - wda;
    Wlds[t] = make_float4(wfa, wfb, wda, wdb);
  }
  __syncthreads();

  const float* sb = src + (size_t)b * bs;
  // phase A: 768 float4-groups over 3*NN positions, <=2 per thread
#pragma unroll
  for (int r = 0; r < 2; ++r) {
    int g = t + 512 * r;
    if (g < 3 * NN / 4) {
      float4 uf = {0.f, 0.f, 0.f, 0.f}, vf = {0.f, 0.f, 0.f, 0.f};
      float4 ud = {0.f, 0.f, 0.f, 0.f}, vd = {0.f, 0.f, 0.f, 0.f};
      for (int i = 0; i < D; ++i) {
        float4 s = *(const float4*)(sb + (size_t)i * 3 * NN + (g << 2));
        float4 w = Wlds[i];
        uf.x += w.x * s.x; uf.y += w.x * s.y; uf.z += w.x * s.z; uf.w += w.x * s.w;
        vf.x += w.y * s.x; vf.y += w.y * s.y; vf.z += w.y * s.z; vf.w += w.y * s.w;
        ud.x += w.z * s.x; ud.y += w.z * s.y; ud.z += w.z * s.z; ud.w += w.z * s.w;
        vd.x += w.w * s.x; vd.y += w.w * s.y; vd.z += w.w * s.z; vd.w += w.w * s.w;
      }
      *(float4*)&Ulds[(g << 2) + 0] = make_float4(uf.x, ud.x, uf.y, ud.y);
      *(float4*)&Ulds[(g << 2) + 2] = make_float4(uf.z, ud.z, uf.w, ud.w);
      *(float4*)&Vlds[(g << 2) + 0] = make_float4(vf.x, vd.x, vf.y, vd.y);
      *(float4*)&Vlds[(g << 2) + 2] = make_float4(vf.z, vd.z, vf.w, vd.w);
    }
  }
  __syncthreads();

  const float inv_k = 1.f / KK;
  // phase B: all 1024 n, 2 per thread
#pragma unroll
  for (int rep = 0; rep < 2; ++rep) {
    int n = rep * 512 + t;
    float2 v0 = Vlds[n];
    float2 v1 = Vlds[NN + n];
    float2 v2 = Vlds[2 * NN + n];
    const int4* ip = (const int4*)(idx + (b * NN + n) * KK);
    float a0 = 0.f, a1 = 0.f, a2 = 0.f;
#pragma unroll
    for (int q = 0; q < 5; ++q) {
      int4 iv = ip[q];
      int nbs[4] = {iv.x, iv.y, iv.z, iv.w};
#pragma unroll
      for (int jj = 0; jj < 4; ++jj) {
        int nb = nbs[jj];
        float2 u0 = Ulds[nb];
        float2 u1 = Ulds[NN + nb];
        float2 u2 = Ulds[2 * NN + nb];
        float pf0 = u0.x + v0.x, pd0 = u0.y + v0.y;
        float pf1 = u1.x + v1.x, pd1 = u1.y + v1.y;
        float pf2 = u2.x + v2.x, pd2 = u2.y + v2.y;
        float dot = pf0 * pd0 + pf1 * pd1 + pf2 * pd2;
        float dsq = pd0 * pd0 + pd1 * pd1 + pd2 * pd2;
        float g = (dot >= 0.f) ? 0.f : 0.8f * dot / (dsq + 1e-6f);
        a0 += pf0 - g * pd0;
        a1 += pf1 - g * pd1;
        a2 += pf2 - g * pd2;
      }
    }
    size_t ob = (size_t)b * CCAT * 3 * NN + (size_t)(ooff + o) * 3 * NN + n;
    xcat[ob] = a0 * inv_k;
    xcat[ob + NN] = a1 * inv_k;
    xcat[ob + 2 * NN] = a2 * inv_k;
  }
}

// ---------------- fused final GEMM + dvec + VN-leakyrelu + partial n-sum ----
// 512 threads / 8 waves. Thread tile 2o x 4n x 3c (24 FMA per f2). dv[c][n]
// computed once per block by threads t<192. No min-blocks hint (R3/R4 lesson).
__global__ __launch_bounds__(512) void final_fused_kernel(
    const float* __restrict__ xcat, const float* __restrict__ Wf4,
    const float* __restrict__ Wd4, float* __restrict__ part) {
  __shared__ float Ws[32][64];     // [f][o_col]
  __shared__ float Xs[3][32][64];  // [c][f][n_col]
  __shared__ float Wda[192];       // Wd4 padded to 6*32
  __shared__ float dvlds[192];     // dv[c][n] for the 64 n-cols
  int b = blockIdx.z;
  int o0 = blockIdx.y * 64;
  int n0 = blockIdx.x * 64;
  int t = threadIdx.x;
  int tx = t & 15, ty = t >> 4;  // compute: n = n0+tx*4+j, o = o0+ty*2+i
  int fr = t >> 4, fc = t & 15;  // staging: f-row, col-group

  if (t < 192) Wda[t] = (t < CCAT) ? Wd4[t] : 0.f;

  float acc[3][2][4];  // [c][o_i][n_j]
#pragma unroll
  for (int c = 0; c < 3; ++c)
#pragma unroll
    for (int i = 0; i < 2; ++i)
#pragma unroll
      for (int j = 0; j < 4; ++j) acc[c][i][j] = 0.f;
  float dvacc = 0.f;  // for t<192: owns (c=t>>6, n=t&63)
  int dc = t >> 6, dn = t & 63;

  const float* xb = xcat + (size_t)b * CCAT * 3 * NN;
  const int NTILE = (CCAT + 31) / 32;  // 6

  for (int tt = 0; tt < NTILE; ++tt) {
    int f = tt * 32 + fr;
    float4 xv[3];
    float wv[4];
#pragma unroll
    for (int c = 0; c < 3; ++c) {
      xv[c] = make_float4(0.f, 0.f, 0.f, 0.f);
      if (f < CCAT)
        xv[c] = *(const float4*)(xb + ((size_t)f * 3 + c) * NN + n0 + (fc << 2));
    }
#pragma unroll
    for (int q = 0; q < 4; ++q) {
      int o = o0 + (fc << 2) + q;
      wv[q] = (o < 341 && f < CCAT) ? Wf4[(size_t)o * CCAT + f] : 0.f;
    }
    __syncthreads();  // previous tile's compute + dv-pass done
#pragma unroll
    for (int c = 0; c < 3; ++c) *(float4*)&Xs[c][fr][fc << 2] = xv[c];
    *(float4*)&Ws[fr][fc << 2] = make_float4(wv[0], wv[1], wv[2], wv[3]);
    __syncthreads();
#pragma unroll
    for (int f2 = 0; f2 < 32; ++f2) {
      float2 w = *(const float2*)&Ws[f2][ty << 1];
#pragma unroll
      for (int c = 0; c < 3; ++c) {
        float4 x = *(const float4*)&Xs[c][f2][tx << 2];
        float xa[4] = {x.x, x.y, x.z, x.w};
#pragma unroll
        for (int j = 0; j < 4; ++j) {
          acc[c][0][j] += w.x * xa[j];
          acc[c][1][j] += w.y * xa[j];
        }
      }
    }
    if (t < 192) {
#pragma unroll
      for (int f2 = 0; f2 < 32; ++f2)
        dvacc += Wda[tt * 32 + f2] * Xs[dc][f2][dn];
    }
  }

  if (t < 192) dvlds[t] = dvacc;
  __syncthreads();
  float dvv[3][4];
#pragma unroll
  for (int c = 0; c < 3; ++c)
#pragma unroll
    for (int j = 0; j < 4; ++j) dvv[c][j] = dvlds[c * 64 + (tx << 2) + j];

  float s[3][2];
#pragma unroll
  for (int c = 0; c < 3; ++c)
#pragma unroll
    for (int i = 0; i < 2; ++i) s[c][i] = 0.f;
#pragma unroll
  for (int i = 0; i < 2; ++i) {
#pragma unroll
    for (int j = 0; j < 4; ++j) {
      float d0 = dvv[0][j], d1 = dvv[1][j], d2 = dvv[2][j];
      float p0 = acc[0][i][j], p1 = acc[1][i][j], p2 = acc[2][i][j];
      float dot = p0 * d0 + p1 * d1 + p2 * d2;
      float dsq = d0 * d0 + d1 * d1 + d2 * d2;
      float g = (dot >= 0.f) ? 0.f : 0.8f * dot / (dsq + 1e-6f);
      s[0][i] += p0 - g * d0;
      s[1][i] += p1 - g * d1;
      s[2][i] += p2 - g * d2;
    }
  }

#pragma unroll
  for (int off = 1; off < 16; off <<= 1) {
#pragma unroll
    for (int c = 0; c < 3; ++c)
#pragma unroll
      for (int i = 0; i < 2; ++i) s[c][i] += __shfl_xor(s[c][i], off, 64);
  }
  if (tx == 0) {
#pragma unroll
    for (int i = 0; i < 2; ++i) {
      int o = o0 + (ty << 1) + i;
      if (o < 341) {
#pragma unroll
        for (int c = 0; c < 3; ++c)
          part[(((size_t)b * 341 + o) * 3 + c) * NT + blockIdx.x] = s[c][i];
      }
    }
  }
}

__global__ void final_reduce_kernel(const float* __restrict__ part,
                                    float* __restrict__ out) {
  int t = blockIdx.x * 256 + threadIdx.x;
  if (t >= BB * 341 * 3) return;
  const float* p = part + (size_t)t * NT;
  float s = 0.f;
#pragma unroll
  for (int nt = 0; nt < NT; ++nt) s += p[nt];
  out[t] = s * (1.f / 1024.f);
}

extern "C" void kernel_launch(void* const* d_in, const int* in_sizes, int n_in,
                              void* d_out, int out_size, void* d_ws,
                              size_t ws_size, hipStream_t stream) {
  (void)in_sizes; (void)n_in; (void)out_size; (void)ws_size;
  const float* x = (const float*)d_in[0];
  const float* Wf[5] = {(const float*)d_in[1], (const float*)d_in[3],
                        (const float*)d_in[5], (const float*)d_in[7],
                        (const float*)d_in[9]};
  const float* Wd[5] = {(const float*)d_in[2], (const float*)d_in[4],
                        (const float*)d_in[6], (const float*)d_in[8],
                        (const float*)d_in[10]};

  float* ws = (float*)d_ws;
  float* dist = ws;
  float* part = ws;  // dist region dead once final_fused runs
  size_t off = (size_t)BB * NN * NN;
  int* idx = (int*)(ws + off);
  off += (size_t)BB * NN * KK;
  float* xcat = ws + off;

  struct LayerCfg { int D, Co, inoff, ooff; };
  const LayerCfg L[4] = {
      {1, 21, 0, 0},
      {21, 21, 0, 21},
      {21, 42, 21, 42},
      {42, 85, 42, 84},
  };

  for (int l = 0; l < 4; ++l) {
    const float* src = (l == 0) ? x : (xcat + (size_t)L[l].inoff * 3 * NN);
    int bs = (l == 0) ? 3 * NN : CCAT * 3 * NN;
    int D = L[l].D, Co = L[l].Co;

    dist_tile_kernel<<<dim3(36, 1, BB), 256, 0, stream>>>(src, bs, 3 * D, dist);
    topk_kernel<<<(BB * NN) / 4, 256, 0, stream>>>(dist, idx);
    edge_fused_kernel<<<BB * Co, 512, 0, stream>>>(src, bs, D, Co, Wf[l],
                                                   Wd[l], idx, L[l].ooff,
                                                   xcat);
  }

  final_fused_kernel<<<dim3(NT, 6, BB), 512, 0, stream>>>(xcat, Wf[4], Wd[4],
                                                          part);
  final_reduce_kernel<<<(BB * 341 * 3 + 255) / 256, 256, 0, stream>>>(
      part, (float*)d_out);
}

// Round 6
// 431.753 us; speedup vs baseline: 5.3706x; 2.5563x over previous
//
#include <hip/hip_runtime.h>
#include <cstddef>

#define BB 8
#define NN 1024
#define KK 20
#define CCAT 169
#define NT 16  // n-tiles of 64 in final fused GEMM

// ---------------- neg dist, symmetric triangle tiles, norms fused in --------
// dist[b][n][m] = 2*sum_f x[f][n]*x[f][m] - ||x_n||^2 - ||x_m||^2  (symmetric)
__global__ __launch_bounds__(256) void dist_tile_kernel(
    const float* __restrict__ src, int bs, int F, float* __restrict__ dist) {
  __shared__ float As[8][128];
  __shared__ float Bs[8][128];
  int b = blockIdx.z;
  int rem = blockIdx.x, bi = 0;
  while (rem >= 8 - bi) { rem -= 8 - bi; ++bi; }
  int bj = bi + rem;
  int n0 = bi * 128;
  int m0 = bj * 128;
  int t = threadIdx.x;
  int tx = t & 15, ty = t >> 4;
  const float* p = src + (size_t)b * bs;

  float acc[8][8];
  float xn[8], xm[8];
#pragma unroll
  for (int i = 0; i < 8; ++i) {
    xn[i] = 0.f;
    xm[i] = 0.f;
#pragma unroll
    for (int j = 0; j < 8; ++j) acc[i][j] = 0.f;
  }

  int fr = t >> 5;
  int cc = (t & 31) << 2;
  for (int f0 = 0; f0 < F; f0 += 8) {
    int f = f0 + fr;
    float4 av = {0.f, 0.f, 0.f, 0.f}, bv = {0.f, 0.f, 0.f, 0.f};
    if (f < F) {
      av = *(const float4*)(p + (size_t)f * NN + n0 + cc);
      bv = *(const float4*)(p + (size_t)f * NN + m0 + cc);
    }
    __syncthreads();
    *(float4*)&As[fr][cc] = av;
    *(float4*)&Bs[fr][cc] = bv;
    __syncthreads();
#pragma unroll
    for (int f2 = 0; f2 < 8; ++f2) {
      float4 al = *(const float4*)&As[f2][ty << 2];
      float4 ah = *(const float4*)&As[f2][64 + (ty << 2)];
      float4 bl = *(const float4*)&Bs[f2][tx << 2];
      float4 bh = *(const float4*)&Bs[f2][64 + (tx << 2)];
      float a[8] = {al.x, al.y, al.z, al.w, ah.x, ah.y, ah.z, ah.w};
      float bb[8] = {bl.x, bl.y, bl.z, bl.w, bh.x, bh.y, bh.z, bh.w};
#pragma unroll
      for (int i = 0; i < 8; ++i) xn[i] += a[i] * a[i];
#pragma unroll
      for (int j = 0; j < 8; ++j) xm[j] += bb[j] * bb[j];
#pragma unroll
      for (int i = 0; i < 8; ++i)
#pragma unroll
        for (int j = 0; j < 8; ++j) acc[i][j] += a[i] * bb[j];
    }
  }

#pragma unroll
  for (int i = 0; i < 8; ++i)
#pragma unroll
    for (int j = 0; j < 8; ++j) acc[i][j] = 2.f * acc[i][j] - xn[i] - xm[j];

#pragma unroll
  for (int i = 0; i < 8; ++i) {
    int n = n0 + ((i < 4) ? ((ty << 2) + i) : (64 + (ty << 2) + i - 4));
    float* dr = dist + (((size_t)b * NN + n) << 10);
    *(float4*)(dr + m0 + (tx << 2)) =
        make_float4(acc[i][0], acc[i][1], acc[i][2], acc[i][3]);
    *(float4*)(dr + m0 + 64 + (tx << 2)) =
        make_float4(acc[i][4], acc[i][5], acc[i][6], acc[i][7]);
  }

  if (bi != bj) {
#pragma unroll
    for (int j = 0; j < 8; ++j) {
      int m = m0 + ((j < 4) ? ((tx << 2) + j) : (64 + (tx << 2) + j - 4));
      float* dr = dist + (((size_t)b * NN + m) << 10);
      *(float4*)(dr + n0 + (ty << 2)) =
          make_float4(acc[0][j], acc[1][j], acc[2][j], acc[3][j]);
      *(float4*)(dr + n0 + 64 + (ty << 2)) =
          make_float4(acc[4][j], acc[5][j], acc[6][j], acc[7][j]);
    }
  }
}

// ---------------- top-k (k=20) per row, one wave per row ----------------
__device__ __forceinline__ unsigned long long shfl_xor_u64(
    unsigned long long v, int off) {
  unsigned lo = (unsigned)v, hi = (unsigned)(v >> 32);
  lo = __shfl_xor(lo, off, 64);
  hi = __shfl_xor(hi, off, 64);
  return ((unsigned long long)hi << 32) | lo;
}

__global__ __launch_bounds__(256) void topk_kernel(
    const float* __restrict__ dist, int* __restrict__ idx_out) {
  int wave = threadIdx.x >> 6;
  int lane = threadIdx.x & 63;
  int row = blockIdx.x * 4 + wave;
  const float* d = dist + ((size_t)row << 10);

  unsigned long long key[16];
#pragma unroll
  for (int s = 0; s < 16; ++s) {
    int m = lane + (s << 6);
    unsigned u = __float_as_uint(d[m]);
    u = (u & 0x80000000u) ? ~u : (u | 0x80000000u);
    key[s] = ((unsigned long long)u << 32) | (unsigned)(NN - 1 - m);
  }

#pragma unroll
  for (int size = 2; size <= 16; size <<= 1) {
#pragma unroll
    for (int stride = size >> 1; stride > 0; stride >>= 1) {
#pragma unroll
      for (int i = 0; i < 16; ++i) {
        int j = i ^ stride;
        if (j > i) {
          unsigned long long a = key[i], c = key[j];
          bool desc = ((i & size) == 0);
          bool sw = desc ? (a < c) : (a > c);
          key[i] = sw ? c : a;
          key[j] = sw ? a : c;
        }
      }
    }
  }

  int* out = idx_out + row * KK;
  unsigned long long head = key[0];
  for (int r = 0; r < KK; ++r) {
    unsigned long long w = head;
#pragma unroll
    for (int off = 32; off > 0; off >>= 1) {
      unsigned long long o = shfl_xor_u64(w, off);
      if (o > w) w = o;
    }
    if (lane == 0) out[r] = (NN - 1) - (int)(w & 0xFFFFFFFFull);
    if (head == w) {
#pragma unroll
      for (int s = 0; s < 15; ++s) key[s] = key[s + 1];
      key[15] = 0ull;
      head = key[0];
    }
  }
}

// ---------------- fused transform + edge combine + mean over k --------------
// 256 threads (512-thread variants spilled — R3/R4/R5). n-split: blockIdx.y
// selects a NN/nsplit slice of phase B; phase A (full U,V) is recomputed per
// slice. Redundancy is cheap exactly where grids are small (small D layers),
// and the split brings layer-1/2 grids from 168 blocks (0.65/CU) to 672.
__global__ __launch_bounds__(256) void edge_fused_kernel(
    const float* __restrict__ src, int bs, int D, int Co, int nsplit,
    const float* __restrict__ Wf, const float* __restrict__ Wd,
    const int* __restrict__ idx, int ooff, float* __restrict__ xcat) {
  __shared__ float2 Ulds[3 * NN];  // 24 KB {Uf,Ud}
  __shared__ float2 Vlds[3 * NN];  // 24 KB {Vf,Vd}
  __shared__ float4 Wlds[48];      // {wfa, wfb, wda, wdb} per i, D<=42
  int bo = blockIdx.x;
  int b = bo / Co, o = bo % Co;
  int t = threadIdx.x;

  if (t < D) {
    float wfa = Wf[o * 2 * D + t];
    float wfb = Wf[o * 2 * D + D + t] - wfa;
    float wda = Wd[o * 2 * D + t];
    float wdb = Wd[o * 2 * D + D + t] - wda;
    Wlds[t] = make_float4(wfa, wfb, wda, wdb);
  }
  __syncthreads();

  const float* sb = src + (size_t)b * bs;
  // phase A: 768 float4-groups over the 3*NN positions, 3 per thread
#pragma unroll
  for (int r = 0; r < 3; ++r) {
    int g = t + 256 * r;
    float4 uf = {0.f, 0.f, 0.f, 0.f}, vf = {0.f, 0.f, 0.f, 0.f};
    float4 ud = {0.f, 0.f, 0.f, 0.f}, vd = {0.f, 0.f, 0.f, 0.f};
    for (int i = 0; i < D; ++i) {
      float4 s = *(const float4*)(sb + (size_t)i * 3 * NN + (g << 2));
      float4 w = Wlds[i];
      uf.x += w.x * s.x; uf.y += w.x * s.y; uf.z += w.x * s.z; uf.w += w.x * s.w;
      vf.x += w.y * s.x; vf.y += w.y * s.y; vf.z += w.y * s.z; vf.w += w.y * s.w;
      ud.x += w.z * s.x; ud.y += w.z * s.y; ud.z += w.z * s.z; ud.w += w.z * s.w;
      vd.x += w.w * s.x; vd.y += w.w * s.y; vd.z += w.w * s.z; vd.w += w.w * s.w;
    }
    *(float4*)&Ulds[(g << 2) + 0] = make_float4(uf.x, ud.x, uf.y, ud.y);
    *(float4*)&Ulds[(g << 2) + 2] = make_float4(uf.z, ud.z, uf.w, ud.w);
    *(float4*)&Vlds[(g << 2) + 0] = make_float4(vf.x, vd.x, vf.y, vd.y);
    *(float4*)&Vlds[(g << 2) + 2] = make_float4(vf.z, vd.z, vf.w, vd.w);
  }
  __syncthreads();

  const float inv_k = 1.f / KK;
  // phase B: this block's n-slice
  int cnt = NN / nsplit;
  int nbase = blockIdx.y * cnt;
  for (int n = nbase + t; n < nbase + cnt; n += 256) {
    float2 v0 = Vlds[n];
    float2 v1 = Vlds[NN + n];
    float2 v2 = Vlds[2 * NN + n];
    const int4* ip = (const int4*)(idx + (b * NN + n) * KK);
    float a0 = 0.f, a1 = 0.f, a2 = 0.f;
#pragma unroll
    for (int q = 0; q < 5; ++q) {
      int4 iv = ip[q];
      int nbs[4] = {iv.x, iv.y, iv.z, iv.w};
#pragma unroll
      for (int jj = 0; jj < 4; ++jj) {
        int nb = nbs[jj];
        float2 u0 = Ulds[nb];
        float2 u1 = Ulds[NN + nb];
        float2 u2 = Ulds[2 * NN + nb];
        float pf0 = u0.x + v0.x, pd0 = u0.y + v0.y;
        float pf1 = u1.x + v1.x, pd1 = u1.y + v1.y;
        float pf2 = u2.x + v2.x, pd2 = u2.y + v2.y;
        float dot = pf0 * pd0 + pf1 * pd1 + pf2 * pd2;
        float dsq = pd0 * pd0 + pd1 * pd1 + pd2 * pd2;
        float g = (dot >= 0.f) ? 0.f : 0.8f * dot / (dsq + 1e-6f);
        a0 += pf0 - g * pd0;
        a1 += pf1 - g * pd1;
        a2 += pf2 - g * pd2;
      }
    }
    size_t ob = (size_t)b * CCAT * 3 * NN + (size_t)(ooff + o) * 3 * NN + n;
    xcat[ob] = a0 * inv_k;
    xcat[ob + NN] = a1 * inv_k;
    xcat[ob + 2 * NN] = a2 * inv_k;
  }
}

// ---------------- fused final GEMM + dvec + VN-leakyrelu + partial n-sum ----
// R0 version verbatim: 256 threads, BK=16, simple two-barrier loop. 73.4 µs,
// VGPR 120, no spill. (512-thread variants spilled to scratch — R3/R4/R5.)
__global__ __launch_bounds__(256) void final_fused_kernel(
    const float* __restrict__ xcat, const float* __restrict__ Wf4,
    const float* __restrict__ Wd4, float* __restrict__ part) {
  __shared__ float Ws[16][64];
  __shared__ float Xs[3][16][64];
  __shared__ float Wds[16];
  int b = blockIdx.z;
  int o0 = blockIdx.y * 64;
  int n0 = blockIdx.x * 64;
  int t = threadIdx.x;
  int tx = t & 15, ty = t >> 4;

  float acc[3][4][4];  // [c][o_i][n_j]
  float dv[3][4];      // [c][n_j]
#pragma unroll
  for (int c = 0; c < 3; ++c) {
#pragma unroll
    for (int i = 0; i < 4; ++i)
#pragma unroll
      for (int j = 0; j < 4; ++j) acc[c][i][j] = 0.f;
#pragma unroll
    for (int j = 0; j < 4; ++j) dv[c][j] = 0.f;
  }

  const float* xb = xcat + (size_t)b * CCAT * 3 * NN;
  for (int f0 = 0; f0 < CCAT; f0 += 16) {
    int f = f0 + ty;
    float4 xv[3];
#pragma unroll
    for (int c = 0; c < 3; ++c) {
      xv[c] = make_float4(0.f, 0.f, 0.f, 0.f);
      if (f < CCAT)
        xv[c] = *(const float4*)(xb + ((size_t)f * 3 + c) * NN + n0 + (tx << 2));
    }
    float wv[4];
#pragma unroll
    for (int q = 0; q < 4; ++q) {
      int o = o0 + (tx << 2) + q;
      wv[q] = (o < 341 && f < CCAT) ? Wf4[o * CCAT + f] : 0.f;
    }
    float wdv = 0.f;
    if (t < 16 && f0 + t < CCAT) wdv = Wd4[f0 + t];
    __syncthreads();
#pragma unroll
    for (int c = 0; c < 3; ++c) *(float4*)&Xs[c][ty][tx << 2] = xv[c];
    *(float4*)&Ws[ty][tx << 2] = make_float4(wv[0], wv[1], wv[2], wv[3]);
    if (t < 16) Wds[t] = wdv;
    __syncthreads();
#pragma unroll
    for (int f2 = 0; f2 < 16; ++f2) {
      float4 w = *(const float4*)&Ws[f2][ty << 2];
      float wa[4] = {w.x, w.y, w.z, w.w};
      float wd = Wds[f2];
#pragma unroll
      for (int c = 0; c < 3; ++c) {
        float4 x = *(const float4*)&Xs[c][f2][tx << 2];
        float xa[4] = {x.x, x.y, x.z, x.w};
#pragma unroll
        for (int j = 0; j < 4; ++j) dv[c][j] += wd * xa[j];
#pragma unroll
        for (int i = 0; i < 4; ++i)
#pragma unroll
          for (int j = 0; j < 4; ++j) acc[c][i][j] += wa[i] * xa[j];
      }
    }
  }

  float s[3][4];
#pragma unroll
  for (int c = 0; c < 3; ++c)
#pragma unroll
    for (int i = 0; i < 4; ++i) s[c][i] = 0.f;
#pragma unroll
  for (int i = 0; i < 4; ++i) {
#pragma unroll
    for (int j = 0; j < 4; ++j) {
      float d0 = dv[0][j], d1 = dv[1][j], d2 = dv[2][j];
      float p0 = acc[0][i][j], p1 = acc[1][i][j], p2 = acc[2][i][j];
      float dot = p0 * d0 + p1 * d1 + p2 * d2;
      float dsq = d0 * d0 + d1 * d1 + d2 * d2;
      float g = (dot >= 0.f) ? 0.f : 0.8f * dot / (dsq + 1e-6f);
      s[0][i] += p0 - g * d0;
      s[1][i] += p1 - g * d1;
      s[2][i] += p2 - g * d2;
    }
  }

#pragma unroll
  for (int off = 1; off < 16; off <<= 1) {
#pragma unroll
    for (int c = 0; c < 3; ++c)
#pragma unroll
      for (int i = 0; i < 4; ++i) s[c][i] += __shfl_xor(s[c][i], off, 64);
  }
  if (tx == 0) {
#pragma unroll
    for (int i = 0; i < 4; ++i) {
      int o = o0 + (ty << 2) + i;
      if (o < 341) {
#pragma unroll
        for (int c = 0; c < 3; ++c)
          part[(((size_t)b * 341 + o) * 3 + c) * NT + blockIdx.x] = s[c][i];
      }
    }
  }
}

__global__ void final_reduce_kernel(const float* __restrict__ part,
                                    float* __restrict__ out) {
  int t = blockIdx.x * 256 + threadIdx.x;
  if (t >= BB * 341 * 3) return;
  const float* p = part + (size_t)t * NT;
  float s = 0.f;
#pragma unroll
  for (int nt = 0; nt < NT; ++nt) s += p[nt];
  out[t] = s * (1.f / 1024.f);
}

extern "C" void kernel_launch(void* const* d_in, const int* in_sizes, int n_in,
                              void* d_out, int out_size, void* d_ws,
                              size_t ws_size, hipStream_t stream) {
  (void)in_sizes; (void)n_in; (void)out_size; (void)ws_size;
  const float* x = (const float*)d_in[0];
  const float* Wf[5] = {(const float*)d_in[1], (const float*)d_in[3],
                        (const float*)d_in[5], (const float*)d_in[7],
                        (const float*)d_in[9]};
  const float* Wd[5] = {(const float*)d_in[2], (const float*)d_in[4],
                        (const float*)d_in[6], (const float*)d_in[8],
                        (const float*)d_in[10]};

  float* ws = (float*)d_ws;
  float* dist = ws;
  float* part = ws;  // dist region dead once final_fused runs
  size_t off = (size_t)BB * NN * NN;
  int* idx = (int*)(ws + off);
  off += (size_t)BB * NN * KK;
  float* xcat = ws + off;

  struct LayerCfg { int D, Co, inoff, ooff, nsplit; };
  const LayerCfg L[4] = {
      {1, 21, 0, 0, 4},
      {21, 21, 0, 21, 4},
      {21, 42, 21, 42, 2},
      {42, 85, 42, 84, 1},
  };

  for (int l = 0; l < 4; ++l) {
    const float* src = (l == 0) ? x : (xcat + (size_t)L[l].inoff * 3 * NN);
    int bs = (l == 0) ? 3 * NN : CCAT * 3 * NN;
    int D = L[l].D, Co = L[l].Co;

    dist_tile_kernel<<<dim3(36, 1, BB), 256, 0, stream>>>(src, bs, 3 * D, dist);
    topk_kernel<<<(BB * NN) / 4, 256, 0, stream>>>(dist, idx);
    edge_fused_kernel<<<dim3(BB * Co, L[l].nsplit), 256, 0, stream>>>(
        src, bs, D, Co, L[l].nsplit, Wf[l], Wd[l], idx, L[l].ooff, xcat);
  }

  final_fused_kernel<<<dim3(NT, 6, BB), 256, 0, stream>>>(xcat, Wf[4], Wd[4],
                                                          part);
  final_reduce_kernel<<<(BB * 341 * 3 + 255) / 256, 256, 0, stream>>>(
      part, (float*)d_out);
}